// Round 6
// baseline (293.437 us; speedup 1.0000x reference)
//
#include <hip/hip_runtime.h>

#define K_TAPS   61
#define R_OUT    4
#define BLOCK    256
#define TILE_OUT (BLOCK * R_OUT)            // 1024 outputs per block
#define TILE_IN  (TILE_OUT + K_TAPS - 1)    // 1084 floats staged
#define TILE_IN4 ((TILE_IN + 3) / 4)        // 271 float4
#define WIN      (R_OUT + K_TAPS - 1)       // 64-float window per thread
#define NV       (WIN / 4)                  // 16 x ds_read_b128

__global__ __launch_bounds__(BLOCK)
void SpikeToCalcium_conv1d_kernel(const float* __restrict__ u,
                                  const float* __restrict__ kern,
                                  float* __restrict__ out,
                                  int L, int M, long long total_in)
{
    __shared__ float sx[TILE_IN4 * 4];

    const int t          = threadIdx.x;
    const int row        = blockIdx.y;
    const int tile_start = blockIdx.x * TILE_OUT;

    // ---- Stage tile: coalesced float4, lane-contiguous. Over-read past the
    // row end only feeds masked outputs; guard only the buffer end.
    const long long gbase = (long long)row * L + tile_start;   // L%4==0 -> aligned
    float4* sxv = reinterpret_cast<float4*>(sx);
    for (int v = t; v < TILE_IN4; v += BLOCK) {
        const long long g = gbase + 4LL * v;
        float4 val;
        if (g + 3 < total_in) {
            val = *reinterpret_cast<const float4*>(u + g);
        } else {
            val.x = (g + 0 < total_in) ? u[g + 0] : 0.0f;
            val.y = (g + 1 < total_in) ? u[g + 1] : 0.0f;
            val.z = (g + 2 < total_in) ? u[g + 2] : 0.0f;
            val.w = (g + 3 < total_in) ? u[g + 3] : 0.0f;
        }
        sxv[v] = val;
    }
    __syncthreads();

    // ---- Window-position-ordered FMA block. One ds_read_b128 (16B/lane,
    // lane-contiguous -> conflict-free) feeds up to 16 FMAs; the value dies
    // immediately (no sliding-window movs). Tap index is wave-uniform and
    // compile-time -> s_load into SGPRs.
    float acc[R_OUT] = {0.0f, 0.0f, 0.0f, 0.0f};

#pragma unroll
    for (int i = 0; i < NV; ++i) {
        const float4 x = sxv[t + i];                 // float4 index t+i
        const float xs[4] = {x.x, x.y, x.z, x.w};
#pragma unroll
        for (int j = 0; j < 4; ++j) {
            const int p = 4 * i + j;                 // window position
#pragma unroll
            for (int r = 0; r < R_OUT; ++r) {
                const int k = p - r;                 // tap index (static)
                if (k >= 0 && k < K_TAPS)
                    acc[r] = fmaf(xs[j], kern[K_TAPS - 1 - k], acc[r]);
            }
        }
    }

    // ---- Store 4 outputs as one coalesced float4 (row base 16B-aligned).
    const int obase = tile_start + 4 * t;
    const long long o = (long long)row * M + obase;
    if (obase + R_OUT <= M) {
        *reinterpret_cast<float4*>(out + o) =
            make_float4(acc[0], acc[1], acc[2], acc[3]);
    } else {
#pragma unroll
        for (int r = 0; r < R_OUT; ++r)
            if (obase + r < M) out[o + r] = acc[r];
    }
}

extern "C" void kernel_launch(void* const* d_in, const int* in_sizes, int n_in,
                              void* d_out, int out_size, void* d_ws, size_t ws_size,
                              hipStream_t stream) {
    const float* u    = (const float*)d_in[0];
    const float* kern = (const float*)d_in[1];
    float*       out  = (float*)d_out;

    const long long total_in = (long long)in_sizes[0];
    // total_in = R*L, out_size = R*(L-K+1)  =>  R = (total_in - out_size)/(K-1)
    const int ROWS = (int)((total_in - (long long)out_size) / (K_TAPS - 1)); // 1024
    const int L    = (int)(total_in / ROWS);                                 // 30000
    const int M    = L - K_TAPS + 1;                                         // 29940

    const int blocks_per_row = (M + TILE_OUT - 1) / TILE_OUT;  // 30
    dim3 grid(blocks_per_row, ROWS);
    SpikeToCalcium_conv1d_kernel<<<grid, BLOCK, 0, stream>>>(
        u, kern, out, L, M, total_in);
}

// Round 7
// 225.596 us; speedup vs baseline: 1.3007x; 1.3007x over previous
//
#include <hip/hip_runtime.h>

#define K_TAPS   61
#define R_OUT    4
#define BLOCK    256
#define TILE_OUT (BLOCK * R_OUT)            // 1024 outputs per block
#define TILE_IN  (TILE_OUT + K_TAPS - 1)    // 1084 floats staged
#define TILE_IN4 ((TILE_IN + 3) / 4)        // 271 float4-groups
#define SUBP     272                        // padded sub-array stride (floats)
#define NV       ((R_OUT + K_TAPS - 1) / 4) // 16 float4-groups per window

__global__ __launch_bounds__(BLOCK)
void SpikeToCalcium_conv1d_kernel(const float* __restrict__ u,
                                  const float* __restrict__ kern,
                                  float* __restrict__ out,
                                  int L, int M, long long total_in)
{
    // Structure-of-arrays: sx[j*SUBP + v] = tile[4v + j].
    // Every LDS access (read and write) is a stride-4B b32 -> 2 lanes/bank,
    // conflict-free. All reads use one VGPR address + immediate offsets.
    __shared__ float sx[4 * SUBP];

    const int t          = threadIdx.x;
    const int row        = blockIdx.y;
    const int tile_start = blockIdx.x * TILE_OUT;

    // ---- Stage tile: coalesced float4 global loads, de-interleaved b32
    // LDS writes (lane-stride 4B each). Over-read past the row end only
    // feeds masked outputs; guard only the buffer end.
    const long long gbase = (long long)row * L + tile_start;   // L%4==0 -> aligned
    for (int v = t; v < TILE_IN4; v += BLOCK) {
        const long long g = gbase + 4LL * v;
        float4 val;
        if (g + 3 < total_in) {
            val = *reinterpret_cast<const float4*>(u + g);
        } else {
            val.x = (g + 0 < total_in) ? u[g + 0] : 0.0f;
            val.y = (g + 1 < total_in) ? u[g + 1] : 0.0f;
            val.z = (g + 2 < total_in) ? u[g + 2] : 0.0f;
            val.w = (g + 3 < total_in) ? u[g + 3] : 0.0f;
        }
        sx[0 * SUBP + v] = val.x;
        sx[1 * SUBP + v] = val.y;
        sx[2 * SUBP + v] = val.z;
        sx[3 * SUBP + v] = val.w;
    }
    __syncthreads();

    // ---- Window-position-ordered FMA block. x = sub[j][t+i] = tile[4t + p],
    // p = 4i+j. Each x feeds up to R_OUT FMAs then dies (no sliding-window
    // movs). Taps are wave-uniform compile-time indices -> SGPR s_loads.
    float acc[R_OUT] = {0.0f, 0.0f, 0.0f, 0.0f};

#pragma unroll
    for (int i = 0; i < NV; ++i) {
#pragma unroll
        for (int j = 0; j < 4; ++j) {
            const float x = sx[j * SUBP + t + i];    // ds_read_b32, imm offset
            const int p = 4 * i + j;                 // window position
#pragma unroll
            for (int r = 0; r < R_OUT; ++r) {
                const int k = p - r;                 // tap index (static)
                if (k >= 0 && k < K_TAPS)
                    acc[r] = fmaf(x, kern[K_TAPS - 1 - k], acc[r]);
            }
        }
    }

    // ---- Store 4 outputs as one coalesced float4 (row base 16B-aligned).
    const int obase = tile_start + 4 * t;
    const long long o = (long long)row * M + obase;
    if (obase + R_OUT <= M) {
        *reinterpret_cast<float4*>(out + o) =
            make_float4(acc[0], acc[1], acc[2], acc[3]);
    } else {
#pragma unroll
        for (int r = 0; r < R_OUT; ++r)
            if (obase + r < M) out[o + r] = acc[r];
    }
}

extern "C" void kernel_launch(void* const* d_in, const int* in_sizes, int n_in,
                              void* d_out, int out_size, void* d_ws, size_t ws_size,
                              hipStream_t stream) {
    const float* u    = (const float*)d_in[0];
    const float* kern = (const float*)d_in[1];
    float*       out  = (float*)d_out;

    const long long total_in = (long long)in_sizes[0];
    // total_in = R*L, out_size = R*(L-K+1)  =>  R = (total_in - out_size)/(K-1)
    const int ROWS = (int)((total_in - (long long)out_size) / (K_TAPS - 1)); // 1024
    const int L    = (int)(total_in / ROWS);                                 // 30000
    const int M    = L - K_TAPS + 1;                                         // 29940

    const int blocks_per_row = (M + TILE_OUT - 1) / TILE_OUT;  // 30
    dim3 grid(blocks_per_row, ROWS);
    SpikeToCalcium_conv1d_kernel<<<grid, BLOCK, 0, stream>>>(
        u, kern, out, L, M, total_in);
}